// Round 1
// baseline (5187.351 us; speedup 1.0000x reference)
//
#include <hip/hip_runtime.h>

#define BB 32
#define SS 256
#define EMBD 256
#define HIDD 512
#define NTAG 45
#define TPAD 48
#define KDIM 768
#define KPAD 776          // 768 + 8 bf16 pad (16B-odd row stride -> conflict-free b128)
#define NBLK 64           // blocks per direction
#define GRID_REC 128

typedef __bf16 bf16x8 __attribute__((ext_vector_type(8)));
typedef float  f32x4  __attribute__((ext_vector_type(4)));
typedef short  s16x8  __attribute__((ext_vector_type(8)));

__device__ __forceinline__ unsigned short f2bf(float x) {
  unsigned u = __builtin_bit_cast(unsigned, x);
  u = (u + 0x7fffu + ((u >> 16) & 1u)) >> 16;  // RNE
  return (unsigned short)u;
}

// ---------- pack: embeddings -> bf16 [t][b][e] ----------
__global__ void k_pack_e(const int* __restrict__ x, const float* __restrict__ emb,
                         unsigned short* __restrict__ E) {
  int idx = blockIdx.x * 256 + threadIdx.x;       // exact: S*B*EMB threads
  int e = idx & 255; int bt = idx >> 8; int b = bt & 31; int t = bt >> 5;
  int tok = x[b * SS + t];
  E[idx] = f2bf(emb[(long)tok * EMBD + e]);
}

// ---------- pack: fused [W_hh | W_ih] bf16, gate-interleaved per block ----------
// Wp[dir][blk][r][k], r = gate*8 + hcol_local, hcol = blk*8 + hcol_local
__global__ void k_pack_w(const float* __restrict__ wih_f, const float* __restrict__ whh_f,
                         const float* __restrict__ bf_,  const float* __restrict__ wih_b,
                         const float* __restrict__ whh_b, const float* __restrict__ bb_,
                         unsigned short* __restrict__ Wp, float* __restrict__ Bp) {
  long idx = (long)blockIdx.x * 256 + threadIdx.x; // exact: 2*64*32*768
  int k = (int)(idx % 768); long rest = idx / 768;
  int r = (int)(rest & 31); rest >>= 5;
  int blk = (int)(rest & 63); int dir = (int)(rest >> 6);
  int row = (r >> 3) * HIDD + blk * 8 + (r & 7);   // gate*512 + hcol
  const float* wih = dir ? wih_b : wih_f;
  const float* whh = dir ? whh_b : whh_f;
  float v = (k < HIDD) ? whh[(long)row * HIDD + k] : wih[(long)row * EMBD + (k - HIDD)];
  Wp[idx] = f2bf(v);
  if (k == 0) {
    const float* bias = dir ? bb_ : bf_;
    Bp[(dir * NBLK + blk) * 32 + r] = bias[row];
  }
}

// ---------- pack: lin_w -> bf16 [48][1024] (pad rows zero), lin_b -> [48] ----------
__global__ void k_pack_l(const float* __restrict__ lin_w, const float* __restrict__ lin_b,
                         unsigned short* __restrict__ LW, float* __restrict__ LB) {
  int idx = blockIdx.x * 256 + threadIdx.x;
  if (idx < TPAD * 1024) {
    int tag = idx >> 10; int c = idx & 1023;
    LW[idx] = (tag < NTAG) ? f2bf(lin_w[tag * 1024 + c]) : (unsigned short)0;
  } else if (idx < TPAD * 1024 + TPAD) {
    int tag = idx - TPAD * 1024;
    LB[tag] = (tag < NTAG) ? lin_b[tag] : 0.f;
  }
}

// ---------- persistent bidirectional LSTM recurrence ----------
// 128 blocks: dir = bx>>6, blk = bx&63. Block owns hcols [blk*8, blk*8+8) x 32 batch.
// gates = [h | e_t] @ Wp^T via mfma 16x16x32 bf16; flag-vector barrier per direction.
__launch_bounds__(256)
__global__ void k_rec(const unsigned short* __restrict__ E,
                      const unsigned short* __restrict__ Wp,
                      const float* __restrict__ Bp,
                      unsigned short* __restrict__ H,
                      unsigned int* __restrict__ flg) {
  __shared__ unsigned short W_ls[32 * KPAD];   // 49664 B, resident weight slice
  __shared__ float G_ls[32 * 33];              // gates scratch [batch][row], padded
  __shared__ float bias_ls[32];

  const int tid = threadIdx.x;
  const int bx  = blockIdx.x;
  const int dir = bx >> 6;
  const int blk = bx & 63;

  // one-time stage of weight slice + bias
  {
    const unsigned short* src = Wp + (long)(dir * NBLK + blk) * 32 * 768;
    for (int c = tid; c < 32 * 96; c += 256) {   // 16B chunks
      int r = c / 96, kc = (c % 96) * 8;
      *(s16x8*)&W_ls[r * KPAD + kc] = *(const s16x8*)&src[r * 768 + kc];
    }
    if (tid < 32) bias_ls[tid] = Bp[(dir * NBLK + blk) * 32 + tid];
  }
  __syncthreads();

  const int w = tid >> 6, lane = tid & 63;
  const int lm = lane & 15, quad = lane >> 4;
  const int mt = w >> 1, nt = w & 1;
  const int m    = mt * 16 + lm;     // batch index (A frag rows)
  const int nrow = nt * 16 + lm;     // packed gate row (B frag rows)

  const int gb = tid >> 3, ghl = tid & 7;   // gate-assembly mapping
  float c_state = 0.f;

  unsigned short* Hd = H + (long)dir * SS * BB * HIDD;
  unsigned int* flagd = flg + (long)dir * SS * NBLK;

  for (int t = 0; t < SS; ++t) {
    const int tE = (dir == 0) ? t : (SS - 1 - t);
    const unsigned short* ebase = E + (long)tE * BB * EMBD + (long)m * EMBD;

    f32x4 acc = {0.f, 0.f, 0.f, 0.f};
    // ---- E-part (independent of h_{t-1}): overlap with barrier wait ----
#pragma unroll
    for (int kk = 16; kk < 24; ++kk) {
      int k0 = kk * 32 + quad * 8;
      s16x8 asv = *(const s16x8*)&ebase[k0 - HIDD];
      s16x8 bsv = *(const s16x8*)&W_ls[nrow * KPAD + k0];
      acc = __builtin_amdgcn_mfma_f32_16x16x32_bf16(
          __builtin_bit_cast(bf16x8, asv), __builtin_bit_cast(bf16x8, bsv), acc, 0, 0, 0);
    }
    if (t > 0) {
      // ---- wait for all 64 same-dir blocks' h from step t-1 ----
      if (w == 0) {
        const unsigned int* fl = flagd + (long)(t - 1) * NBLK;
        for (;;) {
          unsigned f = __hip_atomic_load(&fl[lane], __ATOMIC_RELAXED, __HIP_MEMORY_SCOPE_AGENT);
          if (__ballot(f != 0u) == ~0ull) break;
          __builtin_amdgcn_s_sleep(2);
        }
        if (lane == 0) __threadfence();   // acquire: invalidate stale L1/L2
      }
      __syncthreads();
      // ---- h-part ----
      const int hslot = (dir == 0) ? (t - 1) : (SS - t);
      const unsigned short* hbase = Hd + (long)hslot * BB * HIDD + (long)m * HIDD;
#pragma unroll 8
      for (int kk = 0; kk < 16; ++kk) {
        int k0 = kk * 32 + quad * 8;
        s16x8 asv = *(const s16x8*)&hbase[k0];
        s16x8 bsv = *(const s16x8*)&W_ls[nrow * KPAD + k0];
        acc = __builtin_amdgcn_mfma_f32_16x16x32_bf16(
            __builtin_bit_cast(bf16x8, asv), __builtin_bit_cast(bf16x8, bsv), acc, 0, 0, 0);
      }
    }
    // ---- dump gates (+bias) to LDS ----
    {
      float bias = bias_ls[nrow];
#pragma unroll
      for (int r = 0; r < 4; ++r) {
        int mm = mt * 16 + quad * 4 + r;     // C/D: row=(lane>>4)*4+reg, col=lane&15
        G_ls[mm * 33 + nrow] = acc[r] + bias;
      }
    }
    __syncthreads();
    // ---- gate assembly: thread -> (batch gb, hcol ghl); c stays in register ----
    {
      float gi = G_ls[gb * 33 + ghl];
      float gf = G_ls[gb * 33 + 8 + ghl];
      float gg = G_ls[gb * 33 + 16 + ghl];
      float go = G_ls[gb * 33 + 24 + ghl];
      float si = 1.f / (1.f + __expf(-gi));
      float sf = 1.f / (1.f + __expf(-gf));
      float so = 1.f / (1.f + __expf(-go));
      float tg = tanhf(gg);
      c_state = sf * c_state + si * tg;
      float h = so * tanhf(c_state);
      int tslot = (dir == 0) ? t : (SS - 1 - t);
      Hd[(long)tslot * BB * HIDD + (long)gb * HIDD + blk * 8 + ghl] = f2bf(h);
    }
    __syncthreads();                         // all h stores complete (vmcnt drain)
    if (t < SS - 1 && tid == 0) {
      __threadfence();                       // release: push block's h to coherence point
      __hip_atomic_store(&flagd[(long)t * NBLK + blk], 1u,
                         __ATOMIC_RELAXED, __HIP_MEMORY_SCOPE_AGENT);
    }
  }
}

// ---------- emissions: [8192,1024] x [1024,48] bf16 MFMA ----------
__launch_bounds__(256)
__global__ void k_emis(const unsigned short* __restrict__ H,
                       const unsigned short* __restrict__ LW,
                       const float* __restrict__ LB,
                       float* __restrict__ EM) {
  const int row0 = blockIdx.x * 32;
  const int tid = threadIdx.x;
  const int w = tid >> 6, lane = tid & 63;
  const int lm = lane & 15, quad = lane >> 4;
  const unsigned short* Hf = H;
  const unsigned short* Hb = H + (long)SS * BB * HIDD;

  for (int tile = w; tile < 6; tile += 4) {   // M2 x N3 tiles
    int mt = tile / 3, nt = tile % 3;
    int arow = row0 + mt * 16 + lm;
    int nrow = nt * 16 + lm;
    f32x4 acc = {0.f, 0.f, 0.f, 0.f};
#pragma unroll 4
    for (int kk = 0; kk < 32; ++kk) {
      int k0 = kk * 32 + quad * 8;
      s16x8 asv = (k0 < HIDD) ? *(const s16x8*)&Hf[(long)arow * HIDD + k0]
                              : *(const s16x8*)&Hb[(long)arow * HIDD + (k0 - HIDD)];
      s16x8 bsv = *(const s16x8*)&LW[nrow * 1024 + k0];
      acc = __builtin_amdgcn_mfma_f32_16x16x32_bf16(
          __builtin_bit_cast(bf16x8, asv), __builtin_bit_cast(bf16x8, bsv), acc, 0, 0, 0);
    }
    float bias = LB[nrow];
#pragma unroll
    for (int r = 0; r < 4; ++r) {
      int mm = row0 + mt * 16 + quad * 4 + r;
      EM[(long)mm * TPAD + nrow] = acc[r] + bias;
    }
  }
}

// ---------- CRF: one wave per chain ----------
__global__ void k_crf(const int* __restrict__ tags, const float* __restrict__ start_t,
                      const float* __restrict__ end_t, const float* __restrict__ trans,
                      const float* __restrict__ EM, float* __restrict__ chain) {
  __shared__ float T_ls[NTAG * TPAD];
  const int b = blockIdx.x;
  const int lane = threadIdx.x;   // 64 threads
  for (int i = lane; i < NTAG * NTAG; i += 64) {
    T_ls[(i / NTAG) * TPAD + (i % NTAG)] = trans[i];
  }
  __syncthreads();

  // gold path score (t-parallel across lanes)
  float part = 0.f;
  for (int t = lane; t < SS; t += 64) {
    int tg = tags[b * SS + t];
    part += EM[((long)t * BB + b) * TPAD + tg];
    if (t + 1 < SS) part += T_ls[tg * TPAD + tags[b * SS + t + 1]];
    if (t == 0)      part += start_t[tg];
    if (t == SS - 1) part += end_t[tg];
  }
  for (int off = 32; off; off >>= 1) part += __shfl_down(part, off);
  float score = __shfl(part, 0);

  // forward algorithm, alpha[j] in lane j
  const int j = lane;
  float alpha = (j < NTAG) ? (start_t[j] + EM[(long)b * TPAD + j]) : -1e30f;
  for (int t = 1; t < SS; ++t) {
    float mx = -1e30f;
    for (int i = 0; i < NTAG; ++i) {
      float ai = __shfl(alpha, i);
      float v = ai + ((j < NTAG) ? T_ls[i * TPAD + j] : 0.f);
      mx = fmaxf(mx, v);
    }
    float s = 0.f;
    for (int i = 0; i < NTAG; ++i) {
      float ai = __shfl(alpha, i);
      float v = ai + ((j < NTAG) ? T_ls[i * TPAD + j] : 0.f);
      s += __expf(v - mx);
    }
    float na = mx + __logf(s) + ((j < NTAG) ? EM[((long)t * BB + b) * TPAD + j] : 0.f);
    alpha = (j < NTAG) ? na : -1e30f;
  }
  float v = (j < NTAG) ? (alpha + end_t[j]) : -1e30f;
  float mx = v;
  for (int off = 32; off; off >>= 1) mx = fmaxf(mx, __shfl_xor(mx, off));
  float s = __expf(v - mx);
  for (int off = 32; off; off >>= 1) s += __shfl_xor(s, off);
  if (lane == 0) chain[b] = score - (mx + __logf(s));
}

__global__ void k_fin(const float* __restrict__ chain, float* __restrict__ out) {
  int lane = threadIdx.x;
  float v = (lane < BB) ? chain[lane] : 0.f;
  for (int off = 32; off; off >>= 1) v += __shfl_xor(v, off);
  if (lane == 0) out[0] = -v / (float)BB;
}

extern "C" void kernel_launch(void* const* d_in, const int* in_sizes, int n_in,
                              void* d_out, int out_size, void* d_ws, size_t ws_size,
                              hipStream_t stream) {
  const int*   x      = (const int*)d_in[0];
  const int*   tags   = (const int*)d_in[1];
  const float* emb    = (const float*)d_in[2];
  const float* wih_f  = (const float*)d_in[3];
  const float* whh_f  = (const float*)d_in[4];
  const float* b_f    = (const float*)d_in[5];
  const float* wih_b  = (const float*)d_in[6];
  const float* whh_b  = (const float*)d_in[7];
  const float* b_b    = (const float*)d_in[8];
  const float* lin_w  = (const float*)d_in[9];
  const float* lin_b  = (const float*)d_in[10];
  const float* start_t= (const float*)d_in[11];
  const float* end_t  = (const float*)d_in[12];
  const float* trans  = (const float*)d_in[13];

  char* ws = (char*)d_ws;
  size_t off = 0;
  auto alloc = [&](size_t bytes) {
    void* p = ws + off; off = (off + bytes + 255) & ~(size_t)255; return p;
  };
  unsigned int*   flg = (unsigned int*)  alloc((size_t)2 * SS * NBLK * 4);       // 128 KB
  unsigned short* E   = (unsigned short*)alloc((size_t)SS * BB * EMBD * 2);      // 4 MB
  unsigned short* Wp  = (unsigned short*)alloc((size_t)2 * NBLK * 32 * 768 * 2); // 6 MB
  float*          Bp  = (float*)         alloc((size_t)2 * NBLK * 32 * 4);
  unsigned short* H   = (unsigned short*)alloc((size_t)2 * SS * BB * HIDD * 2);  // 16 MB
  unsigned short* LW  = (unsigned short*)alloc((size_t)TPAD * 1024 * 2);
  float*          LB  = (float*)         alloc((size_t)TPAD * 4);
  float*          EM  = (float*)         alloc((size_t)SS * BB * TPAD * 4);      // 1.5 MB
  float*          chain = (float*)       alloc((size_t)BB * 4);

  hipMemsetAsync(flg, 0, (size_t)2 * SS * NBLK * 4, stream);
  k_pack_e<<<dim3((SS * BB * EMBD) / 256), dim3(256), 0, stream>>>(x, emb, E);
  k_pack_w<<<dim3((2 * NBLK * 32 * 768) / 256), dim3(256), 0, stream>>>(
      wih_f, whh_f, b_f, wih_b, whh_b, b_b, Wp, Bp);
  k_pack_l<<<dim3((TPAD * 1024 + TPAD + 255) / 256), dim3(256), 0, stream>>>(
      lin_w, lin_b, LW, LB);

  void* kargs[] = {&E, &Wp, &Bp, &H, &flg};
  hipLaunchCooperativeKernel((const void*)k_rec, dim3(GRID_REC), dim3(256), kargs, 0, stream);

  k_emis<<<dim3((SS * BB) / 32), dim3(256), 0, stream>>>(H, LW, LB, EM);
  k_crf<<<dim3(BB), dim3(64), 0, stream>>>(tags, start_t, end_t, trans, EM, chain);
  k_fin<<<dim3(1), dim3(64), 0, stream>>>(chain, (float*)d_out);
}

// Round 2
// 1351.279 us; speedup vs baseline: 3.8388x; 3.8388x over previous
//
#include <hip/hip_runtime.h>

#define BB 32
#define SS 256
#define EMBD 256
#define HIDD 512
#define NTAG 45
#define TPAD 48
#define KDIM 768
#define KPAD 776          // 768 + 8 bf16 pad (16B-odd row stride -> conflict-free b128)
#define NBLK 64           // blocks per direction
#define GRID_REC 128

typedef __bf16 bf16x8 __attribute__((ext_vector_type(8)));
typedef float  f32x4  __attribute__((ext_vector_type(4)));
typedef short  s16x8  __attribute__((ext_vector_type(8)));

__device__ __forceinline__ unsigned short f2bf(float x) {
  unsigned u = __builtin_bit_cast(unsigned, x);
  u = (u + 0x7fffu + ((u >> 16) & 1u)) >> 16;  // RNE
  return (unsigned short)u;
}

// 2-byte store bypassing L1/L2 -> lands at IF$ (device coherence point).
__device__ __forceinline__ void store_u16_sys(void* p, unsigned v) {
  asm volatile("global_store_short %0, %1, off sc0 sc1" :: "v"(p), "v"(v) : "memory");
}

// ---------- pack: embeddings -> bf16 [t][b][e] ----------
__global__ void k_pack_e(const int* __restrict__ x, const float* __restrict__ emb,
                         unsigned short* __restrict__ E) {
  int idx = blockIdx.x * 256 + threadIdx.x;       // exact: S*B*EMB threads
  int e = idx & 255; int bt = idx >> 8; int b = bt & 31; int t = bt >> 5;
  int tok = x[b * SS + t];
  E[idx] = f2bf(emb[(long)tok * EMBD + e]);
}

// ---------- pack: fused [W_hh | W_ih] bf16, gate-interleaved per block ----------
__global__ void k_pack_w(const float* __restrict__ wih_f, const float* __restrict__ whh_f,
                         const float* __restrict__ bf_,  const float* __restrict__ wih_b,
                         const float* __restrict__ whh_b, const float* __restrict__ bb_,
                         unsigned short* __restrict__ Wp, float* __restrict__ Bp) {
  long idx = (long)blockIdx.x * 256 + threadIdx.x; // exact: 2*64*32*768
  int k = (int)(idx % 768); long rest = idx / 768;
  int r = (int)(rest & 31); rest >>= 5;
  int blk = (int)(rest & 63); int dir = (int)(rest >> 6);
  int row = (r >> 3) * HIDD + blk * 8 + (r & 7);   // gate*512 + hcol
  const float* wih = dir ? wih_b : wih_f;
  const float* whh = dir ? whh_b : whh_f;
  float v = (k < HIDD) ? whh[(long)row * HIDD + k] : wih[(long)row * EMBD + (k - HIDD)];
  Wp[idx] = f2bf(v);
  if (k == 0) {
    const float* bias = dir ? bb_ : bf_;
    Bp[(dir * NBLK + blk) * 32 + r] = bias[row];
  }
}

// ---------- pack: lin_w -> bf16 [48][1024] (pad rows zero), lin_b -> [48] ----------
__global__ void k_pack_l(const float* __restrict__ lin_w, const float* __restrict__ lin_b,
                         unsigned short* __restrict__ LW, float* __restrict__ LB) {
  int idx = blockIdx.x * 256 + threadIdx.x;
  if (idx < TPAD * 1024) {
    int tag = idx >> 10; int c = idx & 1023;
    LW[idx] = (tag < NTAG) ? f2bf(lin_w[tag * 1024 + c]) : (unsigned short)0;
  } else if (idx < TPAD * 1024 + TPAD) {
    int tag = idx - TPAD * 1024;
    LB[tag] = (tag < NTAG) ? lin_b[tag] : 0.f;
  }
}

// ---------- persistent bidirectional LSTM recurrence ----------
// Fence-free protocol: h stores bypass L2 (sc0 sc1 -> IF$). h addresses are
// write-once per (dir,t), so reader L2/L1 can never hold stale lines within a
// launch; one __threadfence at start guards cross-replay staleness. Barrier C's
// vmcnt(0) drain orders h stores before the relaxed agent flag store.
__launch_bounds__(256)
__global__ void k_rec(const unsigned short* __restrict__ E,
                      const unsigned short* __restrict__ Wp,
                      const float* __restrict__ Bp,
                      unsigned short* __restrict__ H,
                      unsigned int* __restrict__ flg) {
  __shared__ unsigned short W_ls[32 * KPAD];   // 49664 B, resident weight slice
  __shared__ float G_ls[32 * 34];              // gates scratch, stride 34: <=2-way banks
  __shared__ float bias_ls[32];

  const int tid = threadIdx.x;
  const int bx  = blockIdx.x;
  const int dir = bx >> 6;
  const int blk = bx & 63;

  {
    const unsigned short* src = Wp + (long)(dir * NBLK + blk) * 32 * 768;
    for (int c = tid; c < 32 * 96; c += 256) {   // 16B chunks
      int r = c / 96, kc = (c % 96) * 8;
      *(s16x8*)&W_ls[r * KPAD + kc] = *(const s16x8*)&src[r * 768 + kc];
    }
    if (tid < 32) bias_ls[tid] = Bp[(dir * NBLK + blk) * 32 + tid];
  }
  __syncthreads();
  __threadfence();   // one-time: invalidate stale lines from a previous replay

  const int w = tid >> 6, lane = tid & 63;
  const int lm = lane & 15, quad = lane >> 4;
  const int mt = w >> 1, nt = w & 1;
  const int m    = mt * 16 + lm;     // batch index (A frag rows)
  const int nrow = nt * 16 + lm;     // packed gate row (B frag rows)

  const int gb  = w * 8 + (lane >> 3);   // gate assembly: wave-local batches
  const int ghl = lane & 7;
  float c_state = 0.f;

  unsigned short* Hd = H + (long)dir * SS * BB * HIDD;
  unsigned int* flagd = flg + (long)dir * SS * NBLK;

  for (int t = 0; t < SS; ++t) {
    const int tE = (dir == 0) ? t : (SS - 1 - t);
    const unsigned short* ebase = E + (long)tE * BB * EMBD + (long)m * EMBD;

    f32x4 acc = {0.f, 0.f, 0.f, 0.f};
    // ---- E-part (independent of h_{t-1}): overlap with barrier wait ----
#pragma unroll
    for (int kk = 16; kk < 24; ++kk) {
      int k0 = kk * 32 + quad * 8;
      s16x8 asv = *(const s16x8*)&ebase[k0 - HIDD];
      s16x8 bsv = *(const s16x8*)&W_ls[nrow * KPAD + k0];
      acc = __builtin_amdgcn_mfma_f32_16x16x32_bf16(
          __builtin_bit_cast(bf16x8, asv), __builtin_bit_cast(bf16x8, bsv), acc, 0, 0, 0);
    }
    if (t > 0) {
      if (w == 0) {
        const unsigned int* fl = flagd + (long)(t - 1) * NBLK;
        for (;;) {
          unsigned f = __hip_atomic_load(&fl[lane], __ATOMIC_RELAXED, __HIP_MEMORY_SCOPE_AGENT);
          if (__ballot(f != 0u) == ~0ull) break;
          __builtin_amdgcn_s_sleep(2);
        }
      }
      __syncthreads();   // barrier A
      const int hslot = (dir == 0) ? (t - 1) : (SS - t);
      const unsigned short* hbase = Hd + (long)hslot * BB * HIDD + (long)m * HIDD;
#pragma unroll 8
      for (int kk = 0; kk < 16; ++kk) {
        int k0 = kk * 32 + quad * 8;
        s16x8 asv = *(const s16x8*)&hbase[k0];
        s16x8 bsv = *(const s16x8*)&W_ls[nrow * KPAD + k0];
        acc = __builtin_amdgcn_mfma_f32_16x16x32_bf16(
            __builtin_bit_cast(bf16x8, asv), __builtin_bit_cast(bf16x8, bsv), acc, 0, 0, 0);
      }
    }
    // ---- dump gates (+bias) to LDS ----
    {
      float bias = bias_ls[nrow];
#pragma unroll
      for (int r = 0; r < 4; ++r) {
        int mm = mt * 16 + quad * 4 + r;     // C/D: row=(lane>>4)*4+reg, col=lane&15
        G_ls[mm * 34 + nrow] = acc[r] + bias;
      }
    }
    __syncthreads();   // barrier B
    {
      float gi = G_ls[gb * 34 + ghl];
      float gf = G_ls[gb * 34 + 8 + ghl];
      float gg = G_ls[gb * 34 + 16 + ghl];
      float go = G_ls[gb * 34 + 24 + ghl];
      float si = 1.f / (1.f + __expf(-gi));
      float sf = 1.f / (1.f + __expf(-gf));
      float so = 1.f / (1.f + __expf(-go));
      float tg = tanhf(gg);
      c_state = sf * c_state + si * tg;
      float h = so * tanhf(c_state);
      int tslot = (dir == 0) ? t : (SS - 1 - t);
      store_u16_sys(&Hd[(long)tslot * BB * HIDD + (long)gb * HIDD + blk * 8 + ghl],
                    (unsigned)f2bf(h));
    }
    __syncthreads();   // barrier C: each wave drains vmcnt -> h stores at IF$
    if (t < SS - 1 && tid == 0) {
      __hip_atomic_store(&flagd[(long)t * NBLK + blk], 1u,
                         __ATOMIC_RELAXED, __HIP_MEMORY_SCOPE_AGENT);
    }
  }
}

// ---------- emissions: [8192,1024] x [1024,48] bf16 MFMA ----------
__launch_bounds__(256)
__global__ void k_emis(const unsigned short* __restrict__ H,
                       const unsigned short* __restrict__ LW,
                       const float* __restrict__ LB,
                       float* __restrict__ EM) {
  const int row0 = blockIdx.x * 32;
  const int tid = threadIdx.x;
  const int w = tid >> 6, lane = tid & 63;
  const int lm = lane & 15, quad = lane >> 4;
  const unsigned short* Hf = H;
  const unsigned short* Hb = H + (long)SS * BB * HIDD;

  for (int tile = w; tile < 6; tile += 4) {   // M2 x N3 tiles
    int mt = tile / 3, nt = tile % 3;
    int arow = row0 + mt * 16 + lm;
    int nrow = nt * 16 + lm;
    f32x4 acc = {0.f, 0.f, 0.f, 0.f};
#pragma unroll 4
    for (int kk = 0; kk < 32; ++kk) {
      int k0 = kk * 32 + quad * 8;
      s16x8 asv = (k0 < HIDD) ? *(const s16x8*)&Hf[(long)arow * HIDD + k0]
                              : *(const s16x8*)&Hb[(long)arow * HIDD + (k0 - HIDD)];
      s16x8 bsv = *(const s16x8*)&LW[nrow * 1024 + k0];
      acc = __builtin_amdgcn_mfma_f32_16x16x32_bf16(
          __builtin_bit_cast(bf16x8, asv), __builtin_bit_cast(bf16x8, bsv), acc, 0, 0, 0);
    }
    float bias = LB[nrow];
#pragma unroll
    for (int r = 0; r < 4; ++r) {
      int mm = row0 + mt * 16 + quad * 4 + r;
      EM[(long)mm * TPAD + nrow] = acc[r] + bias;
    }
  }
}

// ---------- CRF: one wave per chain, scaled (linear-space) forward ----------
// alpha'_j = am + M_j + log( sum_i e^{alpha_i-am} * expT[i][j] ) + e_t[j]
// with am = max_i alpha_i (exact), M_j = max_i T_ij, expT precomputed once.
__global__ void k_crf(const int* __restrict__ tags, const float* __restrict__ start_t,
                      const float* __restrict__ end_t, const float* __restrict__ trans,
                      const float* __restrict__ EM, float* __restrict__ chain) {
  __shared__ float T_ls[NTAG * TPAD];
  __shared__ float ET[48 * 48 + 16];
  __shared__ float P_ls[64];
  const int b = blockIdx.x;
  const int lane = threadIdx.x;   // 64 threads, single wave
  const int j = lane;

  for (int i = lane; i < NTAG * NTAG; i += 64)
    T_ls[(i / NTAG) * TPAD + (i % NTAG)] = trans[i];
  for (int i = lane; i < 48 * 48 + 16; i += 64) ET[i] = 0.f;
  __syncthreads();

  float Mj = -1e30f;
  if (j < NTAG) {
    for (int i = 0; i < NTAG; ++i) Mj = fmaxf(Mj, T_ls[i * TPAD + j]);
    for (int i = 0; i < NTAG; ++i) ET[i * 48 + j] = __expf(T_ls[i * TPAD + j] - Mj);
  }
  __syncthreads();

  // expT column j into registers
  float et[48];
#pragma unroll
  for (int i = 0; i < 48; ++i) et[i] = ET[i * 48 + j];

  // gold path score (t-parallel across lanes)
  float part = 0.f;
  for (int t = lane; t < SS; t += 64) {
    int tg = tags[b * SS + t];
    part += EM[((long)t * BB + b) * TPAD + tg];
    if (t + 1 < SS) part += T_ls[tg * TPAD + tags[b * SS + t + 1]];
    if (t == 0)      part += start_t[tg];
    if (t == SS - 1) part += end_t[tg];
  }
  for (int off = 32; off; off >>= 1) part += __shfl_down(part, off);
  float score = __shfl(part, 0);

  // forward recurrence
  float alpha = (j < NTAG) ? (start_t[j] + EM[(long)b * TPAD + j]) : -1e30f;
  float e_next = (j < NTAG) ? EM[((long)BB + b) * TPAD + j] : 0.f;
  for (int t = 1; t < SS; ++t) {
    float e_cur = e_next;
    if (t < SS - 1) e_next = (j < NTAG) ? EM[((long)(t + 1) * BB + b) * TPAD + j] : 0.f;
    float am = alpha;
#pragma unroll
    for (int off = 32; off; off >>= 1) am = fmaxf(am, __shfl_xor(am, off));
    float p = __expf(alpha - am);          // lanes >= NTAG: exp(-huge) = 0
    P_ls[lane] = p;
    __builtin_amdgcn_wave_barrier();       // single wave: LDS ops in order
    float s0 = 0.f, s1 = 0.f, s2 = 0.f, s3 = 0.f;
#pragma unroll
    for (int i0 = 0; i0 < 48; i0 += 4) {
      f32x4 pv = *(const f32x4*)&P_ls[i0];
      s0 += pv.x * et[i0];
      s1 += pv.y * et[i0 + 1];
      s2 += pv.z * et[i0 + 2];
      s3 += pv.w * et[i0 + 3];
    }
    __builtin_amdgcn_wave_barrier();       // keep next P_ls write after reads
    float s = (s0 + s1) + (s2 + s3);
    float na = am + Mj + __logf(s) + e_cur;
    alpha = (j < NTAG) ? na : -1e30f;
  }
  float v = (j < NTAG) ? (alpha + end_t[j]) : -1e30f;
  float mx = v;
  for (int off = 32; off; off >>= 1) mx = fmaxf(mx, __shfl_xor(mx, off));
  float s = __expf(v - mx);
  for (int off = 32; off; off >>= 1) s += __shfl_xor(s, off);
  if (lane == 0) chain[b] = score - (mx + __logf(s));
}

__global__ void k_fin(const float* __restrict__ chain, float* __restrict__ out) {
  int lane = threadIdx.x;
  float v = (lane < BB) ? chain[lane] : 0.f;
  for (int off = 32; off; off >>= 1) v += __shfl_xor(v, off);
  if (lane == 0) out[0] = -v / (float)BB;
}

extern "C" void kernel_launch(void* const* d_in, const int* in_sizes, int n_in,
                              void* d_out, int out_size, void* d_ws, size_t ws_size,
                              hipStream_t stream) {
  const int*   x      = (const int*)d_in[0];
  const int*   tags   = (const int*)d_in[1];
  const float* emb    = (const float*)d_in[2];
  const float* wih_f  = (const float*)d_in[3];
  const float* whh_f  = (const float*)d_in[4];
  const float* b_f    = (const float*)d_in[5];
  const float* wih_b  = (const float*)d_in[6];
  const float* whh_b  = (const float*)d_in[7];
  const float* b_b    = (const float*)d_in[8];
  const float* lin_w  = (const float*)d_in[9];
  const float* lin_b  = (const float*)d_in[10];
  const float* start_t= (const float*)d_in[11];
  const float* end_t  = (const float*)d_in[12];
  const float* trans  = (const float*)d_in[13];

  char* ws = (char*)d_ws;
  size_t off = 0;
  auto alloc = [&](size_t bytes) {
    void* p = ws + off; off = (off + bytes + 255) & ~(size_t)255; return p;
  };
  unsigned int*   flg = (unsigned int*)  alloc((size_t)2 * SS * NBLK * 4);       // 128 KB
  unsigned short* E   = (unsigned short*)alloc((size_t)SS * BB * EMBD * 2);      // 4 MB
  unsigned short* Wp  = (unsigned short*)alloc((size_t)2 * NBLK * 32 * 768 * 2); // 6 MB
  float*          Bp  = (float*)         alloc((size_t)2 * NBLK * 32 * 4);
  unsigned short* H   = (unsigned short*)alloc((size_t)2 * SS * BB * HIDD * 2);  // 16 MB
  unsigned short* LW  = (unsigned short*)alloc((size_t)TPAD * 1024 * 2);
  float*          LB  = (float*)         alloc((size_t)TPAD * 4);
  float*          EM  = (float*)         alloc((size_t)SS * BB * TPAD * 4);      // 1.5 MB
  float*          chain = (float*)       alloc((size_t)BB * 4);

  hipMemsetAsync(flg, 0, (size_t)2 * SS * NBLK * 4, stream);
  k_pack_e<<<dim3((SS * BB * EMBD) / 256), dim3(256), 0, stream>>>(x, emb, E);
  k_pack_w<<<dim3((2 * NBLK * 32 * 768) / 256), dim3(256), 0, stream>>>(
      wih_f, whh_f, b_f, wih_b, whh_b, b_b, Wp, Bp);
  k_pack_l<<<dim3((TPAD * 1024 + TPAD + 255) / 256), dim3(256), 0, stream>>>(
      lin_w, lin_b, LW, LB);

  void* kargs[] = {&E, &Wp, &Bp, &H, &flg};
  hipLaunchCooperativeKernel((const void*)k_rec, dim3(GRID_REC), dim3(256), kargs, 0, stream);

  k_emis<<<dim3((SS * BB) / 32), dim3(256), 0, stream>>>(H, LW, LB, EM);
  k_crf<<<dim3(BB), dim3(64), 0, stream>>>(tags, start_t, end_t, trans, EM, chain);
  k_fin<<<dim3(1), dim3(64), 0, stream>>>(chain, (float*)d_out);
}

// Round 3
// 1072.936 us; speedup vs baseline: 4.8347x; 1.2594x over previous
//
#include <hip/hip_runtime.h>

#define BB 32
#define SS 256
#define EMBD 256
#define HIDD 512
#define NTAG 45
#define TPAD 48
#define NBLK 32            // worker blocks per direction (one XCD's worth)
#define ROWS 64            // gate rows per worker block (16 hcols x 4 gates)
#define APAD 520           // 512 + 8 shorts pad -> odd 16B row stride, conflict-free
#define GRID_REC 256

typedef __bf16 bf16x8 __attribute__((ext_vector_type(8)));
typedef float  f32x4  __attribute__((ext_vector_type(4)));
typedef short  s16x8  __attribute__((ext_vector_type(8)));

__device__ __forceinline__ unsigned short f2bf(float x) {
  unsigned u = __builtin_bit_cast(unsigned, x);
  u = (u + 0x7fffu + ((u >> 16) & 1u)) >> 16;  // RNE
  return (unsigned short)u;
}
__device__ __forceinline__ float bf2f(unsigned short u) {
  unsigned v = ((unsigned)u) << 16; return __builtin_bit_cast(float, v);
}

// ---- cpol-controlled scalar ops (fast: sc0 = L2-coherent within XCD;
//      slow: sc0 sc1 = IF$ device-coherent, R2-proven) ----
__device__ __forceinline__ unsigned ld32_cpol(const unsigned* p, bool sys) {
  unsigned v;
  if (sys) asm volatile("global_load_dword %0, %1, off sc0 sc1\ns_waitcnt vmcnt(0)"
                        : "=v"(v) : "v"(p) : "memory");
  else     asm volatile("global_load_dword %0, %1, off sc0\ns_waitcnt vmcnt(0)"
                        : "=v"(v) : "v"(p) : "memory");
  return v;
}
__device__ __forceinline__ void st32_cpol(unsigned* p, unsigned v, bool sys) {
  if (sys) asm volatile("global_store_dword %0, %1, off sc0 sc1" :: "v"(p), "v"(v) : "memory");
  else     asm volatile("global_store_dword %0, %1, off sc0"     :: "v"(p), "v"(v) : "memory");
}

#define LD8(CPOL)                                                           \
  asm volatile("global_load_dwordx4 %0, %[q0], off " CPOL "\n\t"            \
               "global_load_dwordx4 %1, %[q1], off " CPOL "\n\t"            \
               "global_load_dwordx4 %2, %[q2], off " CPOL "\n\t"            \
               "global_load_dwordx4 %3, %[q3], off " CPOL "\n\t"            \
               "global_load_dwordx4 %4, %[q4], off " CPOL "\n\t"            \
               "global_load_dwordx4 %5, %[q5], off " CPOL "\n\t"            \
               "global_load_dwordx4 %6, %[q6], off " CPOL "\n\t"            \
               "global_load_dwordx4 %7, %[q7], off " CPOL "\n\t"            \
               "s_waitcnt vmcnt(0)"                                         \
               : "=&v"(v0), "=&v"(v1), "=&v"(v2), "=&v"(v3),                \
                 "=&v"(v4), "=&v"(v5), "=&v"(v6), "=&v"(v7)                 \
               : [q0] "v"(p), [q1] "v"(p + 2048), [q2] "v"(p + 4096),       \
                 [q3] "v"(p + 6144), [q4] "v"(p + 8192), [q5] "v"(p + 10240),\
                 [q6] "v"(p + 12288), [q7] "v"(p + 14336)                   \
               : "memory")

// ---------- pack: embeddings -> bf16 [t][b][e] ----------
__global__ void k_pack_e(const int* __restrict__ x, const float* __restrict__ emb,
                         unsigned short* __restrict__ E) {
  int idx = blockIdx.x * 256 + threadIdx.x;       // exact: S*B*EMB threads
  int e = idx & 255; int bt = idx >> 8; int b = bt & 31; int t = bt >> 5;
  int tok = x[b * SS + t];
  E[idx] = f2bf(emb[(long)tok * EMBD + e]);
}

// ---------- pack weights ----------
// packed row r2 = blk*64 + gate*16 + hl  <->  orig row gate*512 + blk*16 + hl
// Wh [dir][2048][512] (W_hh), Wie [dir][2048][256] (W_ih), Bh [dir][2048]
__global__ void k_pack_w(const float* __restrict__ wih_f, const float* __restrict__ whh_f,
                         const float* __restrict__ bf_,  const float* __restrict__ wih_b,
                         const float* __restrict__ whh_b, const float* __restrict__ bb_,
                         unsigned short* __restrict__ Wh, unsigned short* __restrict__ Wie,
                         float* __restrict__ Bh) {
  long idx = (long)blockIdx.x * 256 + threadIdx.x; // exact: 2*2048*768
  int k = (int)(idx % 768); long rest = idx / 768;
  int r2 = (int)(rest & 2047); int dir = (int)(rest >> 11);
  int blk = r2 >> 6, rl = r2 & 63, gate = rl >> 4, hl = rl & 15;
  int orig = gate * HIDD + blk * 16 + hl;
  const float* wih = dir ? wih_b : wih_f;
  const float* whh = dir ? whh_b : whh_f;
  if (k < HIDD) Wh[((long)(dir * 2048 + r2)) * 512 + k] = f2bf(whh[(long)orig * HIDD + k]);
  else          Wie[((long)(dir * 2048 + r2)) * 256 + (k - 512)] = f2bf(wih[(long)orig * EMBD + (k - 512)]);
  if (k == 0) {
    const float* bias = dir ? bb_ : bf_;
    Bh[dir * 2048 + r2] = bias[orig];
  }
}

// ---------- pack: lin_w -> bf16 [48][1024], lin_b -> [48] ----------
__global__ void k_pack_l(const float* __restrict__ lin_w, const float* __restrict__ lin_b,
                         unsigned short* __restrict__ LW, float* __restrict__ LB) {
  int idx = blockIdx.x * 256 + threadIdx.x;
  if (idx < TPAD * 1024) {
    int tag = idx >> 10; int c = idx & 1023;
    LW[idx] = (tag < NTAG) ? f2bf(lin_w[tag * 1024 + c]) : (unsigned short)0;
  } else if (idx < TPAD * 1024 + TPAD) {
    int tag = idx - TPAD * 1024;
    LB[tag] = (tag < NTAG) ? lin_b[tag] : 0.f;
  }
}

// ---------- input projection: Ep[dir][blk][t][b][row64] = E @ Wie^T + b ----------
__launch_bounds__(256)
__global__ void k_eproj(const unsigned short* __restrict__ E,
                        const unsigned short* __restrict__ Wie,
                        const float* __restrict__ Bh,
                        unsigned short* __restrict__ Ep) {
  __shared__ unsigned short W2[64 * 264];   // 264 = 256+8 pad
  const int bx = blockIdx.x;                // 2*32*64 = 4096
  const int tg = bx & 63, blk = (bx >> 6) & 31, dir = bx >> 11;
  const int tid = threadIdx.x;
  const int w = tid >> 6, lane = tid & 63;
  const int lm = lane & 15, quad = lane >> 4;

  { // stage Wie slice [64][256]
    const unsigned short* src = Wie + ((long)(dir * 2048 + blk * 64)) * 256;
    for (int i = 0; i < 8; ++i) {
      int c = i * 256 + tid;             // chunk: row = c>>5, off = c&31
      int row = c >> 5, off = c & 31;
      *(s16x8*)&W2[row * 264 + off * 8] = *(const s16x8*)&src[row * 256 + off * 8];
    }
  }
  __syncthreads();

  f32x4 acc[2][4] = {};
#pragma unroll
  for (int kk = 0; kk < 8; ++kk) {
    s16x8 av[2];
#pragma unroll
    for (int sub = 0; sub < 2; ++sub)
      av[sub] = *(const s16x8*)&E[((long)(tg * 128 + w * 32 + sub * 16 + lm)) * 256 + kk * 32 + quad * 8];
#pragma unroll
    for (int sub = 0; sub < 2; ++sub)
#pragma unroll
      for (int n = 0; n < 4; ++n) {
        s16x8 bs = *(const s16x8*)&W2[(n * 16 + lm) * 264 + kk * 32 + quad * 8];
        acc[sub][n] = __builtin_amdgcn_mfma_f32_16x16x32_bf16(
            __builtin_bit_cast(bf16x8, av[sub]), __builtin_bit_cast(bf16x8, bs), acc[sub][n], 0, 0, 0);
      }
  }
  float bh[4];
#pragma unroll
  for (int n = 0; n < 4; ++n) bh[n] = Bh[dir * 2048 + blk * 64 + n * 16 + lm];
#pragma unroll
  for (int sub = 0; sub < 2; ++sub)
#pragma unroll
    for (int n = 0; n < 4; ++n)
#pragma unroll
      for (int r = 0; r < 4; ++r) {
        int m = w * 32 + sub * 16 + quad * 4 + r;
        int t = tg * 4 + (m >> 5), b = m & 31;
        int row_l = n * 16 + lm;
        Ep[((((long)(dir * 32 + blk) * 256 + t) * 32 + b) * 64) + row_l] =
            f2bf(acc[sub][n][r] + bh[n]);
      }
}

// ---------- persistent bidirectional LSTM recurrence ----------
// 256 blocks; workers: bx%8==0 -> dir0, bx%8==1 -> dir1 (round-robin => one XCD
// per direction). Startup vote via XCC_ID selects fast (XCD-local L2, sc0) or
// slow (IF$, sc0 sc1 = R2-proven) protocol. W_hh slice lives in VGPRs.
__launch_bounds__(256, 1)
__global__ void k_rec(const unsigned short* __restrict__ Wh,
                      const unsigned short* __restrict__ Ep,
                      unsigned short* __restrict__ H,
                      unsigned int* __restrict__ sync) {
  __shared__ unsigned short A_ls[32 * APAD];       // 33280 B: h staging, padded
  __shared__ float G_ls[32 * 66 + 4608];           // gates + pad (forces <=2 blk/CU)
  __shared__ int fast_ls;

  const int bx = blockIdx.x;
  const int role = bx & 7;
  if (role >= 2) return;                 // non-worker
  const int dir = role;
  const int blk = bx >> 3;               // 0..31
  const int tid = threadIdx.x;
  const int w = tid >> 6, lane = tid & 63;
  const int lm = lane & 15, quad = lane >> 4;
  const int mt = w >> 1, nt = w & 1;

  unsigned int* det   = sync;                          // [2][32]
  unsigned int* flags = sync + 64;                     // [2][256][32]

  // ---- W_hh slice into VGPRs: rows blk*64 + nt*32 + ns*16 + lm ----
  s16x8 wb[2][16];
  {
    const unsigned short* wsrc =
        Wh + ((long)(dir * 2048 + blk * 64 + nt * 32 + lm)) * 512 + quad * 8;
#pragma unroll
    for (int ns = 0; ns < 2; ++ns)
#pragma unroll
      for (int kk = 0; kk < 16; ++kk)
        wb[ns][kk] = *(const s16x8*)&wsrc[ns * 16 * 512 + kk * 32];
  }

  // ---- protocol vote: are all 32 same-dir workers on one XCD? ----
  unsigned xcc;
  asm volatile("s_getreg_b32 %0, hwreg(HW_REG_XCC_ID)" : "=s"(xcc));
  if (tid == 0) st32_cpol(&det[dir * 32 + blk], xcc | 0x100u, true);
  if (w == 0) {
    unsigned v;
    for (;;) {
      v = (lane < 32) ? ld32_cpol(&det[dir * 32 + lane], true) : (xcc | 0x100u);
      if (__ballot(v != 0u) == ~0ull) break;
      __builtin_amdgcn_s_sleep(1);
    }
    if (lane == 0) fast_ls = (__ballot(v == (xcc | 0x100u)) == ~0ull) ? 1 : 0;
  }
  __syncthreads();
  const bool fast = (fast_ls != 0);
  __threadfence();   // one-time acquire (slow-path parity with R2)

  const int gb = tid >> 3, hp = tid & 7;   // gate assembly: (batch, hcol pair)
  float c0 = 0.f, c1 = 0.f;

  unsigned short* Hd = H + (long)dir * SS * BB * HIDD;
  unsigned int* flagd = flags + dir * SS * NBLK;
  const unsigned short* Epd = Ep + ((long)(dir * 32 + blk) * 256) * 32 * 64;

  for (int t = 0; t < SS; ++t) {
    const int tE = (dir == 0) ? t : (SS - 1 - t);

    // ---- Ep gate pre-activations (independent of h): issue early ----
    unsigned short epv[8];
    {
      const unsigned short* eb =
          Epd + ((long)tE * 32 + (mt * 16 + quad * 4)) * 64 + nt * 32 + lm;
#pragma unroll
      for (int ns = 0; ns < 2; ++ns)
#pragma unroll
        for (int r = 0; r < 4; ++r) epv[ns * 4 + r] = eb[r * 64 + ns * 16];
    }

    f32x4 acc0 = {0.f, 0.f, 0.f, 0.f}, acc1 = {0.f, 0.f, 0.f, 0.f};
    if (t > 0) {
      // ---- wait for all same-dir blocks' h from step t-1 ----
      if (w == 0) {
        const unsigned int* fl = flagd + (long)(t - 1) * NBLK;
        for (;;) {
          unsigned f = (lane < 32) ? ld32_cpol(&fl[lane], !fast) : 1u;
          if (__ballot(f != 0u) == ~0ull) break;
          __builtin_amdgcn_s_sleep(1);
        }
      }
      __syncthreads();   // A
      // ---- stage h[hslot] (32x512 bf16) into padded LDS ----
      {
        const int hslot = (dir == 0) ? (t - 1) : (SS - t);
        const unsigned short* p = Hd + (long)hslot * BB * HIDD + w * 512 + lane * 8;
        s16x8 v0, v1, v2, v3, v4, v5, v6, v7;
        if (fast) { LD8("sc0"); } else { LD8("sc0 sc1"); }
        unsigned short* d = &A_ls[w * APAD + lane * 8];
        *(s16x8*)(d + 0 * 2080) = v0; *(s16x8*)(d + 1 * 2080) = v1;
        *(s16x8*)(d + 2 * 2080) = v2; *(s16x8*)(d + 3 * 2080) = v3;
        *(s16x8*)(d + 4 * 2080) = v4; *(s16x8*)(d + 5 * 2080) = v5;
        *(s16x8*)(d + 6 * 2080) = v6; *(s16x8*)(d + 7 * 2080) = v7;
      }
      __syncthreads();   // A2
      // ---- h @ W_hh^T : K=512, B from VGPRs ----
#pragma unroll
      for (int kk = 0; kk < 16; ++kk) {
        s16x8 av = *(const s16x8*)&A_ls[(mt * 16 + lm) * APAD + kk * 32 + quad * 8];
        acc0 = __builtin_amdgcn_mfma_f32_16x16x32_bf16(
            __builtin_bit_cast(bf16x8, av), __builtin_bit_cast(bf16x8, wb[0][kk]), acc0, 0, 0, 0);
        acc1 = __builtin_amdgcn_mfma_f32_16x16x32_bf16(
            __builtin_bit_cast(bf16x8, av), __builtin_bit_cast(bf16x8, wb[1][kk]), acc1, 0, 0, 0);
      }
    }
    // ---- gates = acc + Ep -> LDS ----
#pragma unroll
    for (int r = 0; r < 4; ++r) {
      int mm = mt * 16 + quad * 4 + r;     // C/D: row=(lane>>4)*4+reg, col=lane&15
      G_ls[mm * 66 + nt * 32 + lm]      = acc0[r] + bf2f(epv[r]);
      G_ls[mm * 66 + nt * 32 + 16 + lm] = acc1[r] + bf2f(epv[4 + r]);
    }
    __syncthreads();   // B
    // ---- activation: thread -> (batch gb, hcols 2hp, 2hp+1) ----
    {
      float gi0 = G_ls[gb * 66 + 0  + 2 * hp], gi1 = G_ls[gb * 66 + 0  + 2 * hp + 1];
      float gf0 = G_ls[gb * 66 + 16 + 2 * hp], gf1 = G_ls[gb * 66 + 16 + 2 * hp + 1];
      float gg0 = G_ls[gb * 66 + 32 + 2 * hp], gg1 = G_ls[gb * 66 + 32 + 2 * hp + 1];
      float go0 = G_ls[gb * 66 + 48 + 2 * hp], go1 = G_ls[gb * 66 + 48 + 2 * hp + 1];
      float si0 = 1.f / (1.f + __expf(-gi0)), si1 = 1.f / (1.f + __expf(-gi1));
      float sf0 = 1.f / (1.f + __expf(-gf0)), sf1 = 1.f / (1.f + __expf(-gf1));
      float so0 = 1.f / (1.f + __expf(-go0)), so1 = 1.f / (1.f + __expf(-go1));
      float tg0 = tanhf(gg0), tg1 = tanhf(gg1);
      c0 = sf0 * c0 + si0 * tg0;
      c1 = sf1 * c1 + si1 * tg1;
      float h0 = so0 * tanhf(c0), h1 = so1 * tanhf(c1);
      int tslot = (dir == 0) ? t : (SS - 1 - t);
      unsigned hv = (unsigned)f2bf(h0) | ((unsigned)f2bf(h1) << 16);
      st32_cpol((unsigned*)&Hd[(long)tslot * BB * HIDD + (long)gb * HIDD + blk * 16 + 2 * hp],
                hv, !fast);
    }
    __syncthreads();   // C: all waves drained vmcnt -> h visible at protocol point
    if (t < SS - 1 && tid == 0)
      st32_cpol(&flagd[(long)t * NBLK + blk], 1u, !fast);
  }
}

// ---------- emissions: [8192,1024] x [1024,48] bf16 MFMA ----------
__launch_bounds__(256)
__global__ void k_emis(const unsigned short* __restrict__ H,
                       const unsigned short* __restrict__ LW,
                       const float* __restrict__ LB,
                       float* __restrict__ EM) {
  const int row0 = blockIdx.x * 32;
  const int tid = threadIdx.x;
  const int w = tid >> 6, lane = tid & 63;
  const int lm = lane & 15, quad = lane >> 4;
  const unsigned short* Hf = H;
  const unsigned short* Hb = H + (long)SS * BB * HIDD;

  for (int tile = w; tile < 6; tile += 4) {   // M2 x N3 tiles
    int mt = tile / 3, nt = tile % 3;
    int arow = row0 + mt * 16 + lm;
    int nrow = nt * 16 + lm;
    f32x4 acc = {0.f, 0.f, 0.f, 0.f};
#pragma unroll 4
    for (int kk = 0; kk < 32; ++kk) {
      int k0 = kk * 32 + quad * 8;
      s16x8 asv = (k0 < HIDD) ? *(const s16x8*)&Hf[(long)arow * HIDD + k0]
                              : *(const s16x8*)&Hb[(long)arow * HIDD + (k0 - HIDD)];
      s16x8 bsv = *(const s16x8*)&LW[nrow * 1024 + k0];
      acc = __builtin_amdgcn_mfma_f32_16x16x32_bf16(
          __builtin_bit_cast(bf16x8, asv), __builtin_bit_cast(bf16x8, bsv), acc, 0, 0, 0);
    }
    float bias = LB[nrow];
#pragma unroll
    for (int r = 0; r < 4; ++r) {
      int mm = row0 + mt * 16 + quad * 4 + r;
      EM[(long)mm * TPAD + nrow] = acc[r] + bias;
    }
  }
}

// ---------- CRF: one wave per chain, scaled (linear-space) forward ----------
__global__ void k_crf(const int* __restrict__ tags, const float* __restrict__ start_t,
                      const float* __restrict__ end_t, const float* __restrict__ trans,
                      const float* __restrict__ EM, float* __restrict__ chain) {
  __shared__ float T_ls[NTAG * TPAD];
  __shared__ float ET[48 * 48 + 16];
  __shared__ float P_ls[64];
  const int b = blockIdx.x;
  const int lane = threadIdx.x;   // 64 threads, single wave
  const int j = lane;

  for (int i = lane; i < NTAG * NTAG; i += 64)
    T_ls[(i / NTAG) * TPAD + (i % NTAG)] = trans[i];
  for (int i = lane; i < 48 * 48 + 16; i += 64) ET[i] = 0.f;
  __syncthreads();

  float Mj = -1e30f;
  if (j < NTAG) {
    for (int i = 0; i < NTAG; ++i) Mj = fmaxf(Mj, T_ls[i * TPAD + j]);
    for (int i = 0; i < NTAG; ++i) ET[i * 48 + j] = __expf(T_ls[i * TPAD + j] - Mj);
  }
  __syncthreads();

  float et[48];
#pragma unroll
  for (int i = 0; i < 48; ++i) et[i] = ET[i * 48 + j];

  float part = 0.f;
  for (int t = lane; t < SS; t += 64) {
    int tg = tags[b * SS + t];
    part += EM[((long)t * BB + b) * TPAD + tg];
    if (t + 1 < SS) part += T_ls[tg * TPAD + tags[b * SS + t + 1]];
    if (t == 0)      part += start_t[tg];
    if (t == SS - 1) part += end_t[tg];
  }
  for (int off = 32; off; off >>= 1) part += __shfl_down(part, off);
  float score = __shfl(part, 0);

  float alpha = (j < NTAG) ? (start_t[j] + EM[(long)b * TPAD + j]) : -1e30f;
  float e_next = (j < NTAG) ? EM[((long)BB + b) * TPAD + j] : 0.f;
  for (int t = 1; t < SS; ++t) {
    float e_cur = e_next;
    if (t < SS - 1) e_next = (j < NTAG) ? EM[((long)(t + 1) * BB + b) * TPAD + j] : 0.f;
    float am = alpha;
#pragma unroll
    for (int off = 32; off; off >>= 1) am = fmaxf(am, __shfl_xor(am, off));
    float p = __expf(alpha - am);
    P_ls[lane] = p;
    __builtin_amdgcn_wave_barrier();
    float s0 = 0.f, s1 = 0.f, s2 = 0.f, s3 = 0.f;
#pragma unroll
    for (int i0 = 0; i0 < 48; i0 += 4) {
      f32x4 pv = *(const f32x4*)&P_ls[i0];
      s0 += pv.x * et[i0];
      s1 += pv.y * et[i0 + 1];
      s2 += pv.z * et[i0 + 2];
      s3 += pv.w * et[i0 + 3];
    }
    __builtin_amdgcn_wave_barrier();
    float s = (s0 + s1) + (s2 + s3);
    float na = am + Mj + __logf(s) + e_cur;
    alpha = (j < NTAG) ? na : -1e30f;
  }
  float v = (j < NTAG) ? (alpha + end_t[j]) : -1e30f;
  float mx = v;
  for (int off = 32; off; off >>= 1) mx = fmaxf(mx, __shfl_xor(mx, off));
  float s = __expf(v - mx);
  for (int off = 32; off; off >>= 1) s += __shfl_xor(s, off);
  if (lane == 0) chain[b] = score - (mx + __logf(s));
}

__global__ void k_fin(const float* __restrict__ chain, float* __restrict__ out) {
  int lane = threadIdx.x;
  float v = (lane < BB) ? chain[lane] : 0.f;
  for (int off = 32; off; off >>= 1) v += __shfl_xor(v, off);
  if (lane == 0) out[0] = -v / (float)BB;
}

extern "C" void kernel_launch(void* const* d_in, const int* in_sizes, int n_in,
                              void* d_out, int out_size, void* d_ws, size_t ws_size,
                              hipStream_t stream) {
  const int*   x      = (const int*)d_in[0];
  const int*   tags   = (const int*)d_in[1];
  const float* emb    = (const float*)d_in[2];
  const float* wih_f  = (const float*)d_in[3];
  const float* whh_f  = (const float*)d_in[4];
  const float* b_f    = (const float*)d_in[5];
  const float* wih_b  = (const float*)d_in[6];
  const float* whh_b  = (const float*)d_in[7];
  const float* b_b    = (const float*)d_in[8];
  const float* lin_w  = (const float*)d_in[9];
  const float* lin_b  = (const float*)d_in[10];
  const float* start_t= (const float*)d_in[11];
  const float* end_t  = (const float*)d_in[12];
  const float* trans  = (const float*)d_in[13];

  char* ws = (char*)d_ws;
  size_t off = 0;
  auto alloc = [&](size_t bytes) {
    void* p = ws + off; off = (off + bytes + 255) & ~(size_t)255; return p;
  };
  size_t sync_bytes = (64 + 2 * SS * NBLK) * 4;                                  // det + flags
  unsigned int*   sync = (unsigned int*) alloc(sync_bytes);
  unsigned short* E   = (unsigned short*)alloc((size_t)SS * BB * EMBD * 2);      // 4 MB
  unsigned short* Wh  = (unsigned short*)alloc((size_t)2 * 2048 * 512 * 2);      // 4 MB
  unsigned short* Wie = (unsigned short*)alloc((size_t)2 * 2048 * 256 * 2);      // 2 MB
  float*          Bh  = (float*)         alloc((size_t)2 * 2048 * 4);
  unsigned short* Ep  = (unsigned short*)alloc((size_t)2 * 32 * 256 * 32 * 64 * 2); // 67 MB
  unsigned short* H   = (unsigned short*)alloc((size_t)2 * SS * BB * HIDD * 2);  // 16 MB
  unsigned short* LW  = (unsigned short*)alloc((size_t)TPAD * 1024 * 2);
  float*          LB  = (float*)         alloc((size_t)TPAD * 4);
  float*          EM  = (float*)         alloc((size_t)SS * BB * TPAD * 4);      // 1.5 MB
  float*          chain = (float*)       alloc((size_t)BB * 4);

  hipMemsetAsync(sync, 0, sync_bytes, stream);
  k_pack_e<<<dim3((SS * BB * EMBD) / 256), dim3(256), 0, stream>>>(x, emb, E);
  k_pack_w<<<dim3((2 * 2048 * 768) / 256), dim3(256), 0, stream>>>(
      wih_f, whh_f, b_f, wih_b, whh_b, b_b, Wh, Wie, Bh);
  k_pack_l<<<dim3((TPAD * 1024 + TPAD + 255) / 256), dim3(256), 0, stream>>>(
      lin_w, lin_b, LW, LB);
  k_eproj<<<dim3(4096), dim3(256), 0, stream>>>(E, Wie, Bh, Ep);

  void* kargs[] = {&Wh, &Ep, &H, &sync};
  hipLaunchCooperativeKernel((const void*)k_rec, dim3(GRID_REC), dim3(256), kargs, 0, stream);

  k_emis<<<dim3((SS * BB) / 32), dim3(256), 0, stream>>>(H, LW, LB, EM);
  k_crf<<<dim3(BB), dim3(64), 0, stream>>>(tags, start_t, end_t, trans, EM, chain);
  k_fin<<<dim3(1), dim3(64), 0, stream>>>(chain, (float*)d_out);
}